// Round 13
// baseline (552.852 us; speedup 1.0000x reference)
//
#include <hip/hip_runtime.h>

typedef _Float16 half8 __attribute__((ext_vector_type(8)));
typedef _Float16 half4 __attribute__((ext_vector_type(4)));
typedef float f32x4 __attribute__((ext_vector_type(4)));

#define TSTEPS 255
#define R 16
#define BLK 512
#define XSH 104   // input-plane stride (halves): [h(0:64)|x(64:72)|noise(72:88)|zero(88:96)|pad]
#define ASH 72    // a-plane stride (halves)

__device__ __forceinline__ float frcp(float x) { return __builtin_amdgcn_rcpf(x); }

__device__ __forceinline__ f32x4 mfma16(half8 a, half8 b, f32x4 c) {
  return __builtin_amdgcn_mfma_f32_16x16x32_f16(a, b, c, 0, 0, 0);
}

// LDS-only barrier: drain DS ops for cross-wave visibility, but leave global
// loads/stores in flight (register consumers get compiler-inserted vmcnt waits
// at use). Avoids __syncthreads' vmcnt(0) drain that serialized HBM prefetch
// latency into every barrier.
__device__ __forceinline__ void barrier_lds() {
  asm volatile("s_waitcnt lgkmcnt(0)" ::: "memory");
  __builtin_amdgcn_s_barrier();
}

__device__ __forceinline__ float gate_nl(const f32x4& az, const float4& bq, float& cs) {
  float zi = az[0] + bq.x, zf = az[1] + bq.y;
  float zg = az[2] + bq.z, zo = az[3] + bq.w;
  float si = frcp(1.f + __expf(-zi));
  float sf = frcp(1.f + __expf(-zf));
  float so = frcp(1.f + __expf(-zo));
  float ag = fabsf(zg), eg = __expf(-2.f * ag);
  float tg = copysignf((1.f - eg) * frcp(1.f + eg), zg);
  cs = fmaf(sf, cs, si * tg);
  float ac = fabsf(cs), ec = __expf(-2.f * ac);
  float tc = copysignf((1.f - ec) * frcp(1.f + ec), cs);
  return so * tc;
}

__global__ __launch_bounds__(BLK)
void genlstm_kernel(const float* __restrict__ noise,
                    const float* __restrict__ eps,
                    const float* __restrict__ Wx,
                    const float* __restrict__ Wh,
                    const float* __restrict__ bg,
                    const float* __restrict__ Wm1, const float* __restrict__ bm1,
                    const float* __restrict__ Wm2, const float* __restrict__ bm2,
                    const float* __restrict__ Wm3, const float* __restrict__ bm3,
                    const float* __restrict__ Wv1, const float* __restrict__ bv1,
                    const float* __restrict__ Wv2, const float* __restrict__ bv2,
                    const float* __restrict__ Wv3, const float* __restrict__ bv3,
                    float* __restrict__ out)
{
  // parity-double-buffered input planes (h|x|noise|zero), hi/lo f16
  __shared__ __align__(16) _Float16 xh[2][R][XSH];
  __shared__ __align__(16) _Float16 xl[2][R][XSH];
  __shared__ __align__(16) _Float16 a1h[2][R][ASH];
  __shared__ __align__(16) _Float16 a1l[2][R][ASH];
  __shared__ __align__(16) _Float16 a2h[2][R][ASH];
  __shared__ __align__(16) _Float16 a2l[2][R][ASH];

  const int tid  = threadIdx.x;
  const int w    = tid >> 6;   // wave 0..7
  const int l    = tid & 63;
  const int lrow = l & 15;     // tile row/col within 16x16
  const int lq   = l >> 4;     // k-group (8 elems)
  const long rowbase = (long)blockIdx.x * R;

  // ---------- one-time weight fragment staging ----------
  // TRANSPOSED gate: A[gate-row g][k] = Wcat_r[k][ 64*(g&3) + (g>>2) ],
  // k reordered [Wh 0..63 | Wx-x 0..7 | Wx-noise 8..23 | zero].
  // Wave w owns gate-row tiles T=2w,2w+1. C: row 4lq+kk = (hc=4T+lq, gate=kk), col=lrow=batch.
  half8 gAhi[2][3], gAlo[2][3];
  #pragma unroll
  for (int t = 0; t < 2; ++t) {
    const int T = 2 * w + t;
    const int n = 64 * (lrow & 3) + 4 * T + (lrow >> 2);
    #pragma unroll
    for (int kt = 0; kt < 3; ++kt)
      #pragma unroll
      for (int j = 0; j < 8; ++j) {
        int k = 32 * kt + 8 * lq + j;
        float v = 0.f;
        if (k < 64) v = Wh[k * 256 + n];
        else if (k < 88) v = Wx[(k - 64) * 256 + n];
        _Float16 h = (_Float16)v;
        gAhi[t][kt][j] = h;
        gAlo[t][kt][j] = (_Float16)(v - (float)h);
      }
  }

  // MLP tiles (original orientation): chain = w>>2 (0:mu 1:var), N-tile nt = w&3
  const int chain = w >> 2;
  const int nt = w & 3;
  const float* W1 = chain ? Wv1 : Wm1;
  const float* W2 = chain ? Wv2 : Wm2;
  half8 B1hi[2], B1lo[2], B2hi[2], B2lo[2];
  #pragma unroll
  for (int kt = 0; kt < 2; ++kt)
    #pragma unroll
    for (int j = 0; j < 8; ++j) {
      int k = 32 * kt + 8 * lq + j;
      int n = 16 * nt + lrow;
      float v1 = W1[k * 64 + n];
      _Float16 h1 = (_Float16)v1;
      B1hi[kt][j] = h1; B1lo[kt][j] = (_Float16)(v1 - (float)h1);
      float v2 = W2[k * 64 + n];
      _Float16 h2 = (_Float16)v2;
      B2hi[kt][j] = h2; B2lo[kt][j] = (_Float16)(v2 - (float)h2);
    }

  // Transposed heads (used by wave 0 only): A[d][k] = W3[k*8+d], d>=8 zero-padded
  half8 Amhi[2], Amlo[2], Avhi[2], Avlo[2];
  #pragma unroll
  for (int kt = 0; kt < 2; ++kt)
    #pragma unroll
    for (int j = 0; j < 8; ++j) {
      int k = 32 * kt + 8 * lq + j;
      float vm = (lrow < 8) ? Wm3[k * 8 + lrow] : 0.f;
      _Float16 hm = (_Float16)vm;
      Amhi[kt][j] = hm; Amlo[kt][j] = (_Float16)(vm - (float)hm);
      float vv = (lrow < 8) ? Wv3[k * 8 + lrow] : 0.f;
      _Float16 hv = (_Float16)vv;
      Avhi[kt][j] = hv; Avlo[kt][j] = (_Float16)(vv - (float)hv);
    }

  const float bias1 = (chain ? bv1 : bm1)[16 * nt + lrow];
  const float bias2 = (chain ? bv2 : bm2)[16 * nt + lrow];

  // lane owns gate quads of h-cols hc1, hc2 (batch row lrow)
  const int hc1 = 8 * w + lq, hc2 = hc1 + 4;
  const float4 bgA = {bg[hc1], bg[64 + hc1], bg[128 + hc1], bg[192 + hc1]};
  const float4 bgB = {bg[hc2], bg[64 + hc2], bg[128 + hc2], bg[192 + hc2]};

  // head/sampler mapping (wave 0, lanes lq<2): (r=lrow, dims d0..d0+3)
  const int d0 = 4 * (lq & 1);
  const float4 bm3q = *(const float4*)&bm3[d0];
  const float4 bv3q = *(const float4*)&bv3[d0];

  float cst0 = 0.f, cst1 = 0.f;   // c-state (lrow, hc1), (lrow, hc2)
  f32x4 cum4 = {0.f, 0.f, 0.f, 0.f};
  float4 ep4 = {0.f, 0.f, 0.f, 0.f};
  const f32x4 fzero = {0.f, 0.f, 0.f, 0.f};

  // persistent h fragments (h0=0); loaded in S2, consumed by hoisted h-MFMAs
  half8 hHi[2], hLo[2];
  #pragma unroll
  for (int kt = 0; kt < 2; ++kt)
    #pragma unroll
    for (int j = 0; j < 8; ++j) { hHi[kt][j] = (_Float16)0; hLo[kt][j] = (_Float16)0; }

  // ---------- prologue ----------
  for (int i = tid; i < 2 * R * XSH; i += BLK) {
    (&xh[0][0][0])[i] = (_Float16)0;
    (&xl[0][0][0])[i] = (_Float16)0;
  }
  {
    const int r5 = tid >> 3, d5 = tid & 7;
    if (tid < 128) out[((rowbase + r5) * 256) * 8 + d5] = 0.f;  // cumsum row 0
  }

  float4 nz = {0.f, 0.f, 0.f, 0.f};
  if (tid >= 384 && tid < 448) {   // wave 6: noise[0] -> buf[0], prefetch noise[1]
    int idx = tid - 384;
    int r = idx >> 2, j4 = (idx & 3) * 4;
    float4 n0 = *(const float4*)&noise[((rowbase + r) * TSTEPS) * 16 + j4];
    float tmp[4] = {n0.x, n0.y, n0.z, n0.w};
    half4 nh, nl;
    #pragma unroll
    for (int j = 0; j < 4; ++j) {
      _Float16 h = (_Float16)tmp[j];
      nh[j] = h; nl[j] = (_Float16)(tmp[j] - (float)h);
    }
    *(half4*)&xh[0][r][72 + j4] = nh;
    *(half4*)&xl[0][r][72 + j4] = nl;
    nz = *(const float4*)&noise[((rowbase + r) * TSTEPS + 1) * 16 + j4];
  }
  if (w == 0 && lq < 2)
    ep4 = *(const float4*)&eps[((rowbase + lrow) * TSTEPS) * 8 + d0];
  barrier_lds();

  // az carries the h-part of next step's gate z (h0 = 0 -> start at zero)
  f32x4 az0 = fzero, az1 = fzero;

  // ---------- time loop: 4 LDS barriers/step ----------
  for (int ts = 0; ts < TSTEPS; ++ts) {
    const int p = ts & 1, p1 = p ^ 1;

    // ---- S0x: finish gate z with x|noise terms (h-part already accumulated)
    half8 Xhi = *(const half8*)&xh[p][lrow][64 + 8 * lq];
    half8 Xlo = *(const half8*)&xl[p][lrow][64 + 8 * lq];
    az0 = mfma16(gAhi[0][2], Xhi, az0);
    az1 = mfma16(gAhi[1][2], Xhi, az1);
    az0 = mfma16(gAlo[0][2], Xhi, az0);
    az1 = mfma16(gAlo[1][2], Xhi, az1);
    az0 = mfma16(gAhi[0][2], Xlo, az0);
    az1 = mfma16(gAhi[1][2], Xlo, az1);

    // ---- S1: gate nonlinearity from registers; h -> buf[p1]
    {
      float hv = gate_nl(az0, bgA, cst0);
      _Float16 hh = (_Float16)hv;
      xh[p1][lrow][hc1] = hh;
      xl[p1][lrow][hc1] = (_Float16)(hv - (float)hh);
    }
    {
      float hv = gate_nl(az1, bgB, cst1);
      _Float16 hh = (_Float16)hv;
      xh[p1][lrow][hc2] = hh;
      xl[p1][lrow][hc2] = (_Float16)(hv - (float)hh);
    }
    az0 = fzero;
    az1 = fzero;
    if (tid >= 384 && tid < 448) {   // wave 6: noise[ts+1] -> buf[p1]; prefetch ts+2
      int idx = tid - 384;
      int r = idx >> 2, j4 = (idx & 3) * 4;
      float tmp[4] = {nz.x, nz.y, nz.z, nz.w};
      half4 nh, nl;
      #pragma unroll
      for (int j = 0; j < 4; ++j) {
        _Float16 h = (_Float16)tmp[j];
        nh[j] = h; nl[j] = (_Float16)(tmp[j] - (float)h);
      }
      *(half4*)&xh[p1][r][72 + j4] = nh;
      *(half4*)&xl[p1][r][72 + j4] = nl;
      if (ts + 2 < TSTEPS)
        nz = *(const float4*)&noise[((rowbase + r) * TSTEPS + ts + 2) * 16 + j4];
    }
    barrier_lds();  // B: h[ts] + noise[ts+1] complete in buf[p1]

    // ---- S2: MLP layer 1 (h frags feed the hoisted h-MFMAs after D)
    {
      hHi[0] = *(const half8*)&xh[p1][lrow][8 * lq];
      hHi[1] = *(const half8*)&xh[p1][lrow][32 + 8 * lq];
      hLo[0] = *(const half8*)&xl[p1][lrow][8 * lq];
      hLo[1] = *(const half8*)&xl[p1][lrow][32 + 8 * lq];
      f32x4 acc = fzero;
      #pragma unroll
      for (int kt = 0; kt < 2; ++kt) {
        acc = mfma16(hHi[kt], B1hi[kt], acc);
        acc = mfma16(hLo[kt], B1hi[kt], acc);
        acc = mfma16(hHi[kt], B1lo[kt], acc);
      }
      const int r0 = 4 * lq;
      #pragma unroll
      for (int k = 0; k < 4; ++k) {
        float v = fmaxf(acc[k] + bias1, 0.f);
        _Float16 vh = (_Float16)v;
        a1h[chain][r0 + k][16 * nt + lrow] = vh;
        a1l[chain][r0 + k][16 * nt + lrow] = (_Float16)(v - (float)vh);
      }
    }
    barrier_lds();  // C

    // ---- S3: MLP layer 2
    {
      half8 ahi0 = *(const half8*)&a1h[chain][lrow][8 * lq];
      half8 ahi1 = *(const half8*)&a1h[chain][lrow][32 + 8 * lq];
      half8 alo0 = *(const half8*)&a1l[chain][lrow][8 * lq];
      half8 alo1 = *(const half8*)&a1l[chain][lrow][32 + 8 * lq];
      f32x4 acc = fzero;
      acc = mfma16(ahi0, B2hi[0], acc);
      acc = mfma16(alo0, B2hi[0], acc);
      acc = mfma16(ahi0, B2lo[0], acc);
      acc = mfma16(ahi1, B2hi[1], acc);
      acc = mfma16(alo1, B2hi[1], acc);
      acc = mfma16(ahi1, B2lo[1], acc);
      const int r0 = 4 * lq;
      #pragma unroll
      for (int k = 0; k < 4; ++k) {
        float v = fmaxf(acc[k] + bias2, 0.f);
        _Float16 vh = (_Float16)v;
        a2h[chain][r0 + k][16 * nt + lrow] = vh;
        a2l[chain][r0 + k][16 * nt + lrow] = (_Float16)(v - (float)vh);
      }
    }
    barrier_lds();  // D: a2 complete

    // ---- D–E window: hoisted h-part MFMAs of NEXT step's gate (all waves;
    // inputs are register-resident) overlapping the wave-0 head.
    az0 = mfma16(gAhi[0][0], hHi[0], az0);
    az1 = mfma16(gAhi[1][0], hHi[0], az1);
    az0 = mfma16(gAlo[0][0], hHi[0], az0);
    az1 = mfma16(gAlo[1][0], hHi[0], az1);
    az0 = mfma16(gAhi[0][0], hLo[0], az0);
    az1 = mfma16(gAhi[1][0], hLo[0], az1);
    az0 = mfma16(gAhi[0][1], hHi[1], az0);
    az1 = mfma16(gAhi[1][1], hHi[1], az1);
    az0 = mfma16(gAlo[0][1], hHi[1], az0);
    az1 = mfma16(gAlo[1][1], hHi[1], az1);
    az0 = mfma16(gAhi[0][1], hLo[1], az0);
    az1 = mfma16(gAhi[1][1], hLo[1], az1);

    if (w == 0) {  // head + sample + x feedback + out
      half8 b0h0 = *(const half8*)&a2h[0][lrow][8 * lq];
      half8 b0h1 = *(const half8*)&a2h[0][lrow][32 + 8 * lq];
      half8 b0l0 = *(const half8*)&a2l[0][lrow][8 * lq];
      half8 b0l1 = *(const half8*)&a2l[0][lrow][32 + 8 * lq];
      f32x4 accm = fzero;
      accm = mfma16(Amhi[0], b0h0, accm);
      accm = mfma16(Amlo[0], b0h0, accm);
      accm = mfma16(Amhi[0], b0l0, accm);
      accm = mfma16(Amhi[1], b0h1, accm);
      accm = mfma16(Amlo[1], b0h1, accm);
      accm = mfma16(Amhi[1], b0l1, accm);
      half8 b1h0 = *(const half8*)&a2h[1][lrow][8 * lq];
      half8 b1h1 = *(const half8*)&a2h[1][lrow][32 + 8 * lq];
      half8 b1l0 = *(const half8*)&a2l[1][lrow][8 * lq];
      half8 b1l1 = *(const half8*)&a2l[1][lrow][32 + 8 * lq];
      f32x4 accv = fzero;
      accv = mfma16(Avhi[0], b1h0, accv);
      accv = mfma16(Avlo[0], b1h0, accv);
      accv = mfma16(Avhi[0], b1l0, accv);
      accv = mfma16(Avhi[1], b1h1, accv);
      accv = mfma16(Avlo[1], b1h1, accv);
      accv = mfma16(Avhi[1], b1l1, accv);

      float xs0 = fmaf(__expf(0.5f * (accv[0] + bv3q.x)), ep4.x, accm[0] + bm3q.x);
      float xs1 = fmaf(__expf(0.5f * (accv[1] + bv3q.y)), ep4.y, accm[1] + bm3q.y);
      float xs2 = fmaf(__expf(0.5f * (accv[2] + bv3q.z)), ep4.z, accm[2] + bm3q.z);
      float xs3 = fmaf(__expf(0.5f * (accv[3] + bv3q.w)), ep4.w, accm[3] + bm3q.w);
      cum4[0] += xs0; cum4[1] += xs1; cum4[2] += xs2; cum4[3] += xs3;
      if (lq < 2) {
        float xs[4] = {xs0, xs1, xs2, xs3};
        half4 xhv, xlv;
        #pragma unroll
        for (int j = 0; j < 4; ++j) {
          _Float16 hh = (_Float16)xs[j];
          xhv[j] = hh; xlv[j] = (_Float16)(xs[j] - (float)hh);
        }
        *(half4*)&xh[p1][lrow][64 + d0] = xhv;   // LDS write first (guarded by E)
        *(half4*)&xl[p1][lrow][64 + d0] = xlv;
        float4 cv = {cum4[0], cum4[1], cum4[2], cum4[3]};
        *(float4*)&out[((rowbase + lrow) * 256 + ts + 1) * 8 + d0] = cv;  // never drained
        if (ts + 1 < TSTEPS)
          ep4 = *(const float4*)&eps[((rowbase + lrow) * TSTEPS + ts + 1) * 8 + d0];
      }
    }
    barrier_lds();  // E: x[ts] in buf[p1]; next S0 reads buf[p1]
  }
}

extern "C" void kernel_launch(void* const* d_in, const int* in_sizes, int n_in,
                              void* d_out, int out_size, void* d_ws, size_t ws_size,
                              hipStream_t stream) {
  const float* noise = (const float*)d_in[0];
  const float* eps   = (const float*)d_in[1];
  const float* Wx    = (const float*)d_in[2];
  const float* Wh    = (const float*)d_in[3];
  const float* bg    = (const float*)d_in[4];
  const float* Wm1   = (const float*)d_in[5];
  const float* bm1   = (const float*)d_in[6];
  const float* Wm2   = (const float*)d_in[7];
  const float* bm2   = (const float*)d_in[8];
  const float* Wm3   = (const float*)d_in[9];
  const float* bm3   = (const float*)d_in[10];
  const float* Wv1   = (const float*)d_in[11];
  const float* bv1   = (const float*)d_in[12];
  const float* Wv2   = (const float*)d_in[13];
  const float* bv2   = (const float*)d_in[14];
  const float* Wv3   = (const float*)d_in[15];
  const float* bv3   = (const float*)d_in[16];
  float* out = (float*)d_out;

  dim3 grid(4096 / R), block(BLK);
  hipLaunchKernelGGL(genlstm_kernel, grid, block, 0, stream,
                     noise, eps, Wx, Wh, bg, Wm1, bm1, Wm2, bm2, Wm3, bm3,
                     Wv1, bv1, Wv2, bv2, Wv3, bv3, out);
}